// Round 11
// baseline (205.351 us; speedup 1.0000x reference)
//
#include <hip/hip_runtime.h>
#include <hip/hip_fp16.h>

// AudioStructuralAnalyzer fused kernel, round 13.
// vs round 12 (106.5 us): LDS-throughput model confirmed (only LDS cuts move
// dur). This round widens LDS ops to b128 where layout alignment permits:
//  - vpass4 (uint4) for P0->tmp, P1->P3, P2->P0: 144 items x 2rows x 8cols,
//    8 b128 per 16 px (was 16 b64 per 8 px). j3 u->P1 (odd word offset) and
//    x^2 (x halo +2 misaligns float4) stay at r12 widths.
//  - Phase C quad: 324 items, 6 b128 reads per 4 px (u row = 10 uint4).
//  - hpass quad (tid<256, 32 rows x 8 col-quads): 2 b128 per 5-tap window of
//    4 outputs (was 3 b64 per 2). j0h/j1h/j2h/j3h/le/harm; acc[6][4];
//    float4 output stores.
// All per-output arithmetic chains preserved -> absmax stays 0.00390625.

#define F_DIM 256
#define T_DIM 2048
#define B_DIM 8
#define C_DIM 2
#define TILE  32
#define NTHR  512

#define XROWS 40          // x tile: halo 4
#define XS    40          // 10 float4 per row
#define UROWS 38          // (ux,uy): halo 3
#define US    40          // +1 col shift; 10 uint4 per row
#define FROWS 36          // field tiles: halo 2
#define FS    36          // 18 uint2 = 9 uint4 per row
#define FH2   18
#define FH4   9
#define EPSF  1e-10f

template<bool V> struct BoolC { static constexpr bool value = V; };

static __device__ __forceinline__ __half2 pack_h2(float a, float b) {
    auto v = __builtin_amdgcn_cvt_pkrtz(a, b);   // v_cvt_pkrtz_f16_f32
    return *(__half2*)&v;
}
static __device__ __forceinline__ float clamp01(float x) {
    return fminf(fmaxf(x, 0.f), 1.f);
}
static __device__ __forceinline__ __half2 u2h(unsigned v) {
    return *(const __half2*)&v;
}

__global__ __launch_bounds__(512, 4)
void audio_struct_fused(const float* __restrict__ x_in,
                        const float* __restrict__ gk_in,
                        float* __restrict__ out)
{
    __shared__ __align__(16) float   s_x [XROWS*XS];    // 6400 B
    __shared__ __align__(16) __half2 s_u [UROWS*US];    // 6080 B (ux,uy), col-shifted
    __shared__ __align__(16) __half2 s_P0[FROWS*FS];    // 5184 B (trace,diff) -> (sf,cv)v
    __shared__ __align__(16) __half2 s_P1[FROWS*FS];    // 5184 B (sxy,tin) -> (ux,uy)v
    __shared__ __align__(16) __half2 s_P2[FROWS*FS];    // 5184 B (sf,cv)
    __shared__ __align__(16) __half2 s_P3[FROWS*FS];    // 5184 B (sxy,tin)v
    __shared__ __align__(16) float   s_tmp[TILE*FS];    // 4608 B (trace,diff)v -> x^2 v
    // total 37824 B -> 4 blocks/CU

    const int tx  = threadIdx.x;          // 0..31
    const int ty  = threadIdx.y;          // 0..15
    const int tid = ty * 32 + tx;         // 0..511
    const bool hact = (tid < 256);
    const int ryq = tid >> 3;             // 0..31 (hact) hpass row
    const int mq  = tid & 7;              // 0..7        hpass col-quad
    const int t0  = blockIdx.x * TILE;
    const int f0  = blockIdx.y * TILE;
    const int b   = blockIdx.z;

    // 1D gaussian = normalized middle row of the separable 5x5 kernel
    float r0 = gk_in[10], r1 = gk_in[11], r2 = gk_in[12], r3 = gk_in[13], r4 = gk_in[14];
    float winv = __builtin_amdgcn_rcpf(r0 + r1 + r2 + r3 + r4);
    const float w[5] = {r0*winv, r1*winv, r2*winv, r3*winv, r4*winv};
    const __half2 wh2[5] = {pack_h2(w[0],w[0]), pack_h2(w[1],w[1]), pack_h2(w[2],w[2]),
                            pack_h2(w[3],w[3]), pack_h2(w[4],w[4])};
    const __half2 h2z    = pack_h2(0.f, 0.f);
    const __half2 two    = pack_h2(2.f, 2.f);
    const __half2 eighth = pack_h2(0.125f, 0.125f);

    // uint4 row-pair vertical pass: item = 2 out rows x 8 cols, 16B LDS ops.
    auto vpass4 = [&](const __half2* src, __half2* dst) {
        const uint4* s = (const uint4*)src;
        uint4* d = (uint4*)dst;
        for (int idx = tid; idx < 16 * FH4; idx += NTHR) {   // 144 items
            int rg = idx / FH4, p = idx - rg * FH4;
            int base = 2 * rg * FH4 + p;
            uint4 vv[6];
            #pragma unroll
            for (int i = 0; i < 6; ++i) vv[i] = s[base + i * FH4];
            __half2 a0=h2z,a1=h2z,a2=h2z,a3=h2z, b0=h2z,b1=h2z,b2=h2z,b3=h2z;
            #pragma unroll
            for (int i = 0; i < 5; ++i) {
                a0 = __hfma2(wh2[i], u2h(vv[i].x),   a0);
                a1 = __hfma2(wh2[i], u2h(vv[i].y),   a1);
                a2 = __hfma2(wh2[i], u2h(vv[i].z),   a2);
                a3 = __hfma2(wh2[i], u2h(vv[i].w),   a3);
                b0 = __hfma2(wh2[i], u2h(vv[i+1].x), b0);
                b1 = __hfma2(wh2[i], u2h(vv[i+1].y), b1);
                b2 = __hfma2(wh2[i], u2h(vv[i+1].z), b2);
                b3 = __hfma2(wh2[i], u2h(vv[i+1].w), b3);
            }
            uint4 oa, ob;
            oa.x=*(unsigned*)&a0; oa.y=*(unsigned*)&a1; oa.z=*(unsigned*)&a2; oa.w=*(unsigned*)&a3;
            ob.x=*(unsigned*)&b0; ob.y=*(unsigned*)&b1; ob.z=*(unsigned*)&b2; ob.w=*(unsigned*)&b3;
            d[base] = oa;
            d[base + FH4] = ob;
        }
    };

    float acc[6][4];
    #pragma unroll
    for (int k = 0; k < 6; ++k)
        #pragma unroll
        for (int s = 0; s < 4; ++s) acc[k][s] = 0.0f;

    const bool interior = (f0 >= 4) && (f0 + TILE + 4 <= F_DIM) &&
                          (t0 >= 4) && (t0 + TILE + 4 <= T_DIM);

    auto phaseABC = [&](const float* xp, auto FASTC) {
        constexpr bool FAST = decltype(FASTC)::value;

        // ---- Phase A: load x tile + halo 4 ----
        for (int idx = tid; idx < XROWS * 20; idx += NTHR) {
            int r  = idx / 20, c2 = idx - r * 20;
            float2 v;
            if (FAST) {
                v = *(const float2*)(xp + (size_t)(f0 + r - 4) * T_DIM + (t0 + c2 * 2 - 4));
            } else {
                int gf = f0 + r - 4;
                int gt = t0 + c2 * 2 - 4;
                v = make_float2(0.f, 0.f);
                if ((unsigned)gf < (unsigned)F_DIM && (unsigned)gt < (unsigned)T_DIM)
                    v = *(const float2*)(xp + (size_t)gf * T_DIM + gt);
            }
            *(float2*)&s_x[r * XS + c2 * 2] = v;
        }
        __syncthreads();

        // ---- Phase B: even-pair items (r,2m)+(r,2m+1) (as r12) ----
        for (int q = tid; q < UROWS * 19; q += NTHR) {
            int r = q / 19, m = q - r * 19;
            const float2* x2p = (const float2*)s_x;
            int base = r * (XS/2) + m;
            float2 a0 = x2p[base],            b0 = x2p[base + 1];
            float2 a1 = x2p[base + (XS/2)],   b1 = x2p[base + (XS/2) + 1];
            float2 a2 = x2p[base + XS],       b2 = x2p[base + XS + 1];
            float c0 = a2.x - a0.x, c1 = a2.y - a0.y;
            float c2c = b2.x - b0.x, c3 = b2.y - b0.y;
            float s0 = fmaf(2.f, a1.x, a0.x + a2.x);
            float s1 = fmaf(2.f, a1.y, a0.y + a2.y);
            float s2 = fmaf(2.f, b1.x, b0.x + b2.x);
            float s3 = fmaf(2.f, b1.y, b0.y + b2.y);
            float gfvA = (fmaf(2.f, c1, c0) + c2c) * 0.125f;
            float gtvA = (s2 - s0) * 0.125f;
            float gfvB = (fmaf(2.f, c2c, c1) + c3) * 0.125f;
            float gtvB = (s3 - s1) * 0.125f;

            bool rin = (r >= 1) && (r < UROWS - 1);
            int  fiA = (r - 1) * FS + 2 * m - 1;
            int  gfr = f0 + r - 3;
            bool frOK = FAST || ((unsigned)gfr < (unsigned)F_DIM);

            #pragma unroll
            for (int jj = 0; jj < 2; ++jj) {
                float gfv = jj ? gfvB : gfvA;
                float gtv = jj ? gtvB : gtvA;
                int   ccI = 2 * m + jj;
                bool  okI = true;
                if (!FAST) {
                    int gtc = t0 + ccI - 3;
                    okI = frOK & ((unsigned)gtc < (unsigned)T_DIM);
                }
                float ux = 0.f, uy = 0.f, trp = 0.f, dfp = 0.f, sxy = 0.f,
                      tin = 0.f, sf = 0.f;
                if (okI) {
                    float gte = gtv + EPSF;
                    float g2f = gfv * gfv;
                    float d2  = fmaf(gte, gte, g2f);
                    float rh  = __builtin_amdgcn_rsqf(d2);
                    ux = gte * rh;
                    uy = gfv * rh;
                    float m2 = fmaf(gtv, gtv, g2f) + EPSF;
                    trp = m2;
                    dfp = m2 * (ux - uy) * (ux + uy);
                    sxy = m2 * ux * uy;
                    tin = __builtin_amdgcn_rcpf(1.0f + fabsf(gtv));
                    sf  = fabsf(gfv);
                }
                s_u[r * US + ccI + 1] = pack_h2(ux, uy);
                bool pv = rin && (jj ? (m <= 17) : (m >= 1));
                if (pv) {
                    int fi = fiA + jj;
                    s_P0[fi] = pack_h2(trp, dfp);
                    s_P1[fi] = pack_h2(sxy, tin);
                    s_P2[fi] = pack_h2(sf, 0.f);
                }
            }
        }
        __syncthreads();

        // ---- Slot CD1: Phase C quad (u sobel -> P2.y) + vpass4 x2 ----
        for (int q = tid; q < FROWS * FH4; q += NTHR) {   // 324 items
            int r = q / FH4, Q = q - r * FH4;
            const uint4* su4 = (const uint4*)s_u;
            int base = r * 10 + Q;                 // words 40r + 4Q
            uint4 ta4 = su4[base],      tb4 = su4[base + 1];
            uint4 ma4 = su4[base + 10], mb4 = su4[base + 11];
            uint4 ba4 = su4[base + 20], bb4 = su4[base + 21];
            __half2 t_[8] = {u2h(ta4.x),u2h(ta4.y),u2h(ta4.z),u2h(ta4.w),
                             u2h(tb4.x),u2h(tb4.y),u2h(tb4.z),u2h(tb4.w)};
            __half2 m_[8] = {u2h(ma4.x),u2h(ma4.y),u2h(ma4.z),u2h(ma4.w),
                             u2h(mb4.x),u2h(mb4.y),u2h(mb4.z),u2h(mb4.w)};
            __half2 b_[8] = {u2h(ba4.x),u2h(ba4.y),u2h(ba4.z),u2h(ba4.w),
                             u2h(bb4.x),u2h(bb4.y),u2h(bb4.z),u2h(bb4.w)};
            __half2 l_[7];
            #pragma unroll
            for (int k = 1; k <= 6; ++k) {
                __half2 s = __hadd2(t_[k], b_[k]);
                l_[k] = __hfma2(two, m_[k], s);
            }
            int gfr = f0 + r - 2;
            bool frOK = FAST || ((unsigned)gfr < (unsigned)F_DIM);
            #pragma unroll
            for (int jj = 0; jj < 4; ++jj) {
                __half2 tr = __hadd2(t_[jj+1], t_[jj+3]); tr = __hfma2(two, t_[jj+2], tr);
                __half2 br = __hadd2(b_[jj+1], b_[jj+3]); br = __hfma2(two, b_[jj+2], br);
                __half2 dx = __hmul2(__hsub2(l_[jj+3], l_[jj+1]), eighth);
                __half2 dy = __hmul2(__hsub2(br, tr), eighth);
                float2 fx = __half22float2(dx);
                float2 fy = __half22float2(dy);
                float cv = __builtin_amdgcn_sqrtf(
                    fmaf(fx.x, fx.x, fmaf(fx.y, fx.y,
                    fmaf(fy.x, fy.x, fy.y * fy.y))) + EPSF);
                int cc = 4 * Q + jj;
                if (!FAST) {
                    int gtc = t0 + cc - 2;
                    if (!(frOK & ((unsigned)gtc < (unsigned)T_DIM))) cv = 0.f;
                }
                ((__half*)s_P2)[2 * (r * FS + cc) + 1] = __float2half_rn(cv);
            }
        }
        vpass4(s_P0, (__half2*)s_tmp);   // j0 vertical: (trace,diff)
        vpass4(s_P1, s_P3);              // j1 vertical: (sxy,tin)
        __syncthreads();
    };

    for (int c = 0; c < C_DIM; ++c) {
        if (c) __syncthreads();

        const float* xp = x_in + (size_t)(b * C_DIM + c) * F_DIM * T_DIM;
        if (interior) phaseABC(xp, BoolC<true>{});
        else          phaseABC(xp, BoolC<false>{});

        __half2* tmp_h2 = (__half2*)s_tmp;

        // ====== Slot D23: j0h+j1h quad + entropy ; vpass4(P2->P0) ; v(u->P1) ======
        if (hact) {
            const uint4* t4 = (const uint4*)tmp_h2;
            uint4 ua = t4[ryq * FH4 + mq], ub = t4[ryq * FH4 + mq + 1];
            float2 e[8] = {__half22float2(u2h(ua.x)), __half22float2(u2h(ua.y)),
                           __half22float2(u2h(ua.z)), __half22float2(u2h(ua.w)),
                           __half22float2(u2h(ub.x)), __half22float2(u2h(ub.y)),
                           __half22float2(u2h(ub.z)), __half22float2(u2h(ub.w))};
            const uint4* p34 = (const uint4*)s_P3;
            uint4 pa = p34[ryq * FH4 + mq], pb = p34[ryq * FH4 + mq + 1];
            __half2 pe[8] = {u2h(pa.x),u2h(pa.y),u2h(pa.z),u2h(pa.w),
                             u2h(pb.x),u2h(pb.y),u2h(pb.z),u2h(pb.w)};
            #pragma unroll
            for (int jj = 0; jj < 4; ++jj) {
                float trace = w[0]*e[jj].x + w[1]*e[jj+1].x + w[2]*e[jj+2].x
                            + w[3]*e[jj+3].x + w[4]*e[jj+4].x;
                float diff  = w[0]*e[jj].y + w[1]*e[jj+1].y + w[2]*e[jj+2].y
                            + w[3]*e[jj+3].y + w[4]*e[jj+4].y;
                __half2 a = h2z;
                a = __hfma2(wh2[0], pe[jj],     a);
                a = __hfma2(wh2[1], pe[jj + 1], a);
                a = __hfma2(wh2[2], pe[jj + 2], a);
                a = __hfma2(wh2[3], pe[jj + 3], a);
                a = __hfma2(wh2[4], pe[jj + 4], a);
                float2 v = __half22float2(a);          // (vxy_s, tp)
                float disc  = __builtin_amdgcn_sqrtf(
                                  fmaxf(diff * diff + 4.f * v.x * v.x, 0.f) + EPSF);
                float l1 = fmaxf(0.5f * (trace + disc), EPSF);
                float l2 = fmaxf(0.5f * (trace - disc), EPSF);
                float inv = __builtin_amdgcn_rcpf(l1 + l2 + EPSF);
                float p1 = l1 * inv, p2 = l2 * inv;
                float ent = -(p1 * __builtin_amdgcn_logf(p1 + EPSF)
                            + p2 * __builtin_amdgcn_logf(p2 + EPSF));
                acc[0][jj] += 0.5f * clamp01(ent);
                acc[4][jj] += 0.5f * clamp01(v.y);
            }
        }
        vpass4(s_P2, s_P0);              // j2 vertical: (sf,cv) -> P0
        {
            // j3 vertical: u -> P1, row-pair uint2 (odd word offset, as r12)
            const uint2* su2 = (const uint2*)s_u;
            uint2* dP1 = (uint2*)s_P1;
            for (int idx = tid; idx < 16 * FH2; idx += NTHR) {
                int rg = idx / FH2, p = idx - rg * FH2;
                const uint2* sp = su2 + (2 * rg + 1) * (US/2) + 1 + p;
                uint2 vv[6];
                #pragma unroll
                for (int i = 0; i < 6; ++i) vv[i] = sp[i * (US/2)];
                __half2 a0 = h2z, a1 = h2z, b0 = h2z, b1 = h2z;
                #pragma unroll
                for (int i = 0; i < 5; ++i) {
                    a0 = __hfma2(wh2[i], u2h(vv[i].x),     a0);
                    a1 = __hfma2(wh2[i], u2h(vv[i].y),     a1);
                    b0 = __hfma2(wh2[i], u2h(vv[i + 1].x), b0);
                    b1 = __hfma2(wh2[i], u2h(vv[i + 1].y), b1);
                }
                uint2 oa; oa.x = *(const unsigned*)&a0; oa.y = *(const unsigned*)&a1;
                uint2 ob; ob.x = *(const unsigned*)&b0; ob.y = *(const unsigned*)&b1;
                dP1[2 * rg * FH2 + p] = oa;
                dP1[(2 * rg + 1) * FH2 + p] = ob;
            }
        }
        __syncthreads();

        // ====== Slot D45: j2h (P0) + j3h (P1) quad ; v(x^2 -> tmp) ======
        if (hact) {
            const uint4* p04 = (const uint4*)s_P0;
            uint4 qa = p04[ryq * FH4 + mq], qb = p04[ryq * FH4 + mq + 1];
            __half2 qe[8] = {u2h(qa.x),u2h(qa.y),u2h(qa.z),u2h(qa.w),
                             u2h(qb.x),u2h(qb.y),u2h(qb.z),u2h(qb.w)};
            const uint4* p14 = (const uint4*)s_P1;
            uint4 ra = p14[ryq * FH4 + mq], rb = p14[ryq * FH4 + mq + 1];
            __half2 re[8] = {u2h(ra.x),u2h(ra.y),u2h(ra.z),u2h(ra.w),
                             u2h(rb.x),u2h(rb.y),u2h(rb.z),u2h(rb.w)};
            #pragma unroll
            for (int jj = 0; jj < 4; ++jj) {
                __half2 sA = h2z;
                sA = __hfma2(wh2[0], qe[jj],     sA);
                sA = __hfma2(wh2[1], qe[jj + 1], sA);
                sA = __hfma2(wh2[2], qe[jj + 2], sA);
                sA = __hfma2(wh2[3], qe[jj + 3], sA);
                sA = __hfma2(wh2[4], qe[jj + 4], sA);
                float2 sv = __half22float2(sA);        // (sp, cvs)
                acc[5][jj] += 0.5f * clamp01(sv.x);
                acc[2][jj] += 0.5f * sv.y;
                __half2 uA = h2z;
                uA = __hfma2(wh2[0], re[jj],     uA);
                uA = __hfma2(wh2[1], re[jj + 1], uA);
                uA = __hfma2(wh2[2], re[jj + 2], uA);
                uA = __hfma2(wh2[3], re[jj + 3], uA);
                uA = __hfma2(wh2[4], re[jj + 4], uA);
                float2 uv = __half22float2(uA);        // (ua, va)
                acc[1][jj] += 0.5f * clamp01(
                    __builtin_amdgcn_sqrtf(uv.x * uv.x + uv.y * uv.y + EPSF));
            }
        }
        {
            // j4 vertical: x^2 -> tmp, row-pair float2 (as r12)
            const float2* sx2 = (const float2*)s_x;
            float2* dt2 = (float2*)s_tmp;
            for (int idx = tid; idx < 16 * FH2; idx += NTHR) {
                int rg = idx / FH2, p = idx - rg * FH2;
                const float2* sp = sx2 + (2 * rg + 2) * (XS/2) + 1 + p;
                float2 sq[6];
                #pragma unroll
                for (int i = 0; i < 6; ++i) {
                    float2 v = sp[i * (XS/2)];
                    sq[i] = make_float2(v.x * v.x, v.y * v.y);
                }
                float aA = 0.f, bA = 0.f, aB = 0.f, bB = 0.f;
                #pragma unroll
                for (int i = 0; i < 5; ++i) {
                    aA = fmaf(w[i], sq[i].x,     aA);
                    bA = fmaf(w[i], sq[i].y,     bA);
                    aB = fmaf(w[i], sq[i + 1].x, aB);
                    bB = fmaf(w[i], sq[i + 1].y, bB);
                }
                dt2[2 * rg * FH2 + p] = make_float2(aA, bA);
                dt2[(2 * rg + 1) * FH2 + p] = make_float2(aB, bB);
            }
        }
        __syncthreads();

        // ====== Slot D6: j4h (le) quad + harmonic epilogue ======
        if (hact) {
            const float4* tf4 = (const float4*)s_tmp;   // pixels linear, 9 f4/row
            float4 g0 = tf4[ryq * FH4 + mq], g1 = tf4[ryq * FH4 + mq + 1];
            float le[4];
            le[0] = w[0]*g0.x + w[1]*g0.y + w[2]*g0.z + w[3]*g0.w + w[4]*g1.x;
            le[1] = w[0]*g0.y + w[1]*g0.z + w[2]*g0.w + w[3]*g1.x + w[4]*g1.y;
            le[2] = w[0]*g0.z + w[1]*g0.w + w[2]*g1.x + w[3]*g1.y + w[4]*g1.z;
            le[3] = w[0]*g0.w + w[1]*g1.x + w[2]*g1.y + w[3]*g1.z + w[4]*g1.w;
            const float4* sx4 = (const float4*)s_x;     // 10 f4/row
            float4 xm4 = sx4[(ryq + 1) * 10 + mq + 1];
            float4 x04 = sx4[(ryq + 4) * 10 + mq + 1];
            float4 xp4 = sx4[(ryq + 7) * 10 + mq + 1];
            float xmv[4] = {xm4.x, xm4.y, xm4.z, xm4.w};
            float x0v[4] = {x04.x, x04.y, x04.z, x04.w};
            float xpv[4] = {xp4.x, xp4.y, xp4.z, xp4.w};
            #pragma unroll
            for (int jj = 0; jj < 4; ++jj) {
                float harm = fabsf(2.f * x0v[jj] - xmv[jj] - xpv[jj]);
                acc[3][jj] += 0.5f * clamp01(harm * __builtin_amdgcn_rcpf(le[jj] + EPSF));
            }
        }
    }

    // ---- write 6 output planes: one float4 per plane per active thread ----
    if (hact) {
        const size_t plane = (size_t)B_DIM * F_DIM * T_DIM;
        const size_t base  = (size_t)b * F_DIM * T_DIM
                           + (size_t)(f0 + ryq) * T_DIM + t0 + 4 * mq;
        #pragma unroll
        for (int k = 0; k < 6; ++k)
            *(float4*)(out + k * plane + base) =
                make_float4(acc[k][0], acc[k][1], acc[k][2], acc[k][3]);
    }
}

extern "C" void kernel_launch(void* const* d_in, const int* in_sizes, int n_in,
                              void* d_out, int out_size, void* d_ws, size_t ws_size,
                              hipStream_t stream) {
    const float* x  = (const float*)d_in[0];
    const float* gk = (const float*)d_in[1];
    float* out = (float*)d_out;
    dim3 grid(T_DIM / TILE, F_DIM / TILE, B_DIM);   // 64 x 8 x 8 = 4096 blocks
    dim3 block(32, 16);                             // 512 threads = 8 waves
    audio_struct_fused<<<grid, block, 0, stream>>>(x, gk, out);
}

// Round 12
// 200.431 us; speedup vs baseline: 1.0245x; 1.0245x over previous
//
#include <hip/hip_runtime.h>
#include <hip/hip_fp16.h>

// AudioStructuralAnalyzer fused kernel, round 14.
// vs round 13 (110 us, REGRESSION vs r12's 106.5; conflicts 13.6M->18.2M):
//  r13 bundled 3 changes; unbundle and keep only the clean wins on the r12
//  base:
//  - Phase C quad (from r13): 6 b128 reads per 4 px vs 9 b64 per 2 px.
//  - vpass4 (uint4) for the 3 aligned vertical passes P0->tmp, P1->P3,
//    P2->P0 (FS=36 h2 = 9 uint4, rows 16B aligned).
//  - REJECTED from r13: hpass-quad with 256 idle threads (suspected
//    regression source: idles 4/8 waves + stride conflicts). Horizontal
//    passes stay r12 col-pair with all 512 threads; float2 output stores.
//  - NEW: Phase A interior loads as float4 (t0-4 is 16B-aligned), halving
//    A's LDS writes and global instr count.
// Per-output arithmetic chains preserved -> absmax stays 0.00390625.

#define F_DIM 256
#define T_DIM 2048
#define B_DIM 8
#define C_DIM 2
#define TILE  32
#define NTHR  512

#define XROWS 40          // x tile: halo 4
#define XS    40          // 20 float2 / 10 float4 per row
#define UROWS 38          // (ux,uy): halo 3
#define US    40          // +1 col shift; 20 uint2 / 10 uint4 per row
#define FROWS 36          // field tiles: halo 2
#define FS    36          // 18 uint2 = 9 uint4 per row
#define FH2   18
#define FH4   9
#define EPSF  1e-10f

template<bool V> struct BoolC { static constexpr bool value = V; };

static __device__ __forceinline__ __half2 pack_h2(float a, float b) {
    auto v = __builtin_amdgcn_cvt_pkrtz(a, b);   // v_cvt_pkrtz_f16_f32
    return *(__half2*)&v;
}
static __device__ __forceinline__ float clamp01(float x) {
    return fminf(fmaxf(x, 0.f), 1.f);
}
static __device__ __forceinline__ __half2 u2h(unsigned v) {
    return *(const __half2*)&v;
}

__global__ __launch_bounds__(512, 4)
void audio_struct_fused(const float* __restrict__ x_in,
                        const float* __restrict__ gk_in,
                        float* __restrict__ out)
{
    __shared__ __align__(16) float   s_x [XROWS*XS];    // 6400 B
    __shared__ __align__(16) __half2 s_u [UROWS*US];    // 6080 B (ux,uy), col-shifted
    __shared__ __align__(16) __half2 s_P0[FROWS*FS];    // 5184 B (trace,diff) -> (sf,cv)v
    __shared__ __align__(16) __half2 s_P1[FROWS*FS];    // 5184 B (sxy,tin) -> (ux,uy)v
    __shared__ __align__(16) __half2 s_P2[FROWS*FS];    // 5184 B (sf,cv)
    __shared__ __align__(16) __half2 s_P3[FROWS*FS];    // 5184 B (sxy,tin)v
    __shared__ __align__(16) float   s_tmp[TILE*FS];    // 4608 B (trace,diff)v -> x^2 v
    // total 37824 B -> 4 blocks/CU

    const int tx  = threadIdx.x;          // 0..31
    const int ty  = threadIdx.y;          // 0..15
    const int tid = ty * 32 + tx;         // 0..511
    const int ryh = tid >> 4;             // 0..31  hpass row
    const int mch = tid & 15;             // 0..15  hpass col-pair
    const int t0  = blockIdx.x * TILE;
    const int f0  = blockIdx.y * TILE;
    const int b   = blockIdx.z;

    // 1D gaussian = normalized middle row of the separable 5x5 kernel
    float r0 = gk_in[10], r1 = gk_in[11], r2 = gk_in[12], r3 = gk_in[13], r4 = gk_in[14];
    float winv = __builtin_amdgcn_rcpf(r0 + r1 + r2 + r3 + r4);
    const float w[5] = {r0*winv, r1*winv, r2*winv, r3*winv, r4*winv};
    const __half2 wh2[5] = {pack_h2(w[0],w[0]), pack_h2(w[1],w[1]), pack_h2(w[2],w[2]),
                            pack_h2(w[3],w[3]), pack_h2(w[4],w[4])};
    const __half2 h2z    = pack_h2(0.f, 0.f);
    const __half2 two    = pack_h2(2.f, 2.f);
    const __half2 eighth = pack_h2(0.125f, 0.125f);

    // uint4 row-pair vertical pass: item = 2 out rows x 8 cols, 16B LDS ops.
    auto vpass4 = [&](const __half2* src, __half2* dst) {
        const uint4* s = (const uint4*)src;
        uint4* d = (uint4*)dst;
        for (int idx = tid; idx < 16 * FH4; idx += NTHR) {   // 144 items
            int rg = idx / FH4, p = idx - rg * FH4;
            int base = 2 * rg * FH4 + p;
            uint4 vv[6];
            #pragma unroll
            for (int i = 0; i < 6; ++i) vv[i] = s[base + i * FH4];
            __half2 a0=h2z,a1=h2z,a2=h2z,a3=h2z, b0=h2z,b1=h2z,b2=h2z,b3=h2z;
            #pragma unroll
            for (int i = 0; i < 5; ++i) {
                a0 = __hfma2(wh2[i], u2h(vv[i].x),   a0);
                a1 = __hfma2(wh2[i], u2h(vv[i].y),   a1);
                a2 = __hfma2(wh2[i], u2h(vv[i].z),   a2);
                a3 = __hfma2(wh2[i], u2h(vv[i].w),   a3);
                b0 = __hfma2(wh2[i], u2h(vv[i+1].x), b0);
                b1 = __hfma2(wh2[i], u2h(vv[i+1].y), b1);
                b2 = __hfma2(wh2[i], u2h(vv[i+1].z), b2);
                b3 = __hfma2(wh2[i], u2h(vv[i+1].w), b3);
            }
            uint4 oa, ob;
            oa.x=*(unsigned*)&a0; oa.y=*(unsigned*)&a1; oa.z=*(unsigned*)&a2; oa.w=*(unsigned*)&a3;
            ob.x=*(unsigned*)&b0; ob.y=*(unsigned*)&b1; ob.z=*(unsigned*)&b2; ob.w=*(unsigned*)&b3;
            d[base] = oa;
            d[base + FH4] = ob;
        }
    };

    float acc[6][2];     // [plane][col 2mch / 2mch+1]
    #pragma unroll
    for (int k = 0; k < 6; ++k)
        #pragma unroll
        for (int s = 0; s < 2; ++s) acc[k][s] = 0.0f;

    const bool interior = (f0 >= 4) && (f0 + TILE + 4 <= F_DIM) &&
                          (t0 >= 4) && (t0 + TILE + 4 <= T_DIM);

    auto phaseABC = [&](const float* xp, auto FASTC) {
        constexpr bool FAST = decltype(FASTC)::value;

        // ---- Phase A: load x tile + halo 4 ----
        if (FAST) {
            // t0-4 is 16B-aligned (t0 % 32 == 0); rows 8192B -> float4 loads
            for (int idx = tid; idx < XROWS * 10; idx += NTHR) {
                int r  = idx / 10, c4 = idx - r * 10;
                float4 v = *(const float4*)(xp + (size_t)(f0 + r - 4) * T_DIM
                                               + (t0 + c4 * 4 - 4));
                *(float4*)&s_x[r * XS + c4 * 4] = v;
            }
        } else {
            for (int idx = tid; idx < XROWS * 20; idx += NTHR) {
                int r  = idx / 20, c2 = idx - r * 20;
                int gf = f0 + r - 4;
                int gt = t0 + c2 * 2 - 4;
                float2 v = make_float2(0.f, 0.f);
                if ((unsigned)gf < (unsigned)F_DIM && (unsigned)gt < (unsigned)T_DIM)
                    v = *(const float2*)(xp + (size_t)gf * T_DIM + gt);
                *(float2*)&s_x[r * XS + c2 * 2] = v;
            }
        }
        __syncthreads();

        // ---- Phase B: even-pair items (r,2m)+(r,2m+1) (as r12) ----
        for (int q = tid; q < UROWS * 19; q += NTHR) {
            int r = q / 19, m = q - r * 19;
            const float2* x2p = (const float2*)s_x;
            int base = r * (XS/2) + m;
            float2 a0 = x2p[base],            b0 = x2p[base + 1];
            float2 a1 = x2p[base + (XS/2)],   b1 = x2p[base + (XS/2) + 1];
            float2 a2 = x2p[base + XS],       b2 = x2p[base + XS + 1];
            float c0 = a2.x - a0.x, c1 = a2.y - a0.y;
            float c2c = b2.x - b0.x, c3 = b2.y - b0.y;
            float s0 = fmaf(2.f, a1.x, a0.x + a2.x);
            float s1 = fmaf(2.f, a1.y, a0.y + a2.y);
            float s2 = fmaf(2.f, b1.x, b0.x + b2.x);
            float s3 = fmaf(2.f, b1.y, b0.y + b2.y);
            float gfvA = (fmaf(2.f, c1, c0) + c2c) * 0.125f;
            float gtvA = (s2 - s0) * 0.125f;
            float gfvB = (fmaf(2.f, c2c, c1) + c3) * 0.125f;
            float gtvB = (s3 - s1) * 0.125f;

            bool rin = (r >= 1) && (r < UROWS - 1);
            int  fiA = (r - 1) * FS + 2 * m - 1;
            int  gfr = f0 + r - 3;
            bool frOK = FAST || ((unsigned)gfr < (unsigned)F_DIM);

            #pragma unroll
            for (int jj = 0; jj < 2; ++jj) {
                float gfv = jj ? gfvB : gfvA;
                float gtv = jj ? gtvB : gtvA;
                int   ccI = 2 * m + jj;
                bool  okI = true;
                if (!FAST) {
                    int gtc = t0 + ccI - 3;
                    okI = frOK & ((unsigned)gtc < (unsigned)T_DIM);
                }
                float ux = 0.f, uy = 0.f, trp = 0.f, dfp = 0.f, sxy = 0.f,
                      tin = 0.f, sf = 0.f;
                if (okI) {
                    float gte = gtv + EPSF;
                    float g2f = gfv * gfv;
                    float d2  = fmaf(gte, gte, g2f);
                    float rh  = __builtin_amdgcn_rsqf(d2);
                    ux = gte * rh;
                    uy = gfv * rh;
                    float m2 = fmaf(gtv, gtv, g2f) + EPSF;
                    trp = m2;
                    dfp = m2 * (ux - uy) * (ux + uy);
                    sxy = m2 * ux * uy;
                    tin = __builtin_amdgcn_rcpf(1.0f + fabsf(gtv));
                    sf  = fabsf(gfv);
                }
                s_u[r * US + ccI + 1] = pack_h2(ux, uy);
                bool pv = rin && (jj ? (m <= 17) : (m >= 1));
                if (pv) {
                    int fi = fiA + jj;
                    s_P0[fi] = pack_h2(trp, dfp);
                    s_P1[fi] = pack_h2(sxy, tin);
                    s_P2[fi] = pack_h2(sf, 0.f);
                }
            }
        }
        __syncthreads();

        // ---- Slot CD1: Phase C quad (u sobel -> P2.y) + vpass4 x2 ----
        for (int q = tid; q < FROWS * FH4; q += NTHR) {   // 324 items
            int r = q / FH4, Q = q - r * FH4;
            const uint4* su4 = (const uint4*)s_u;
            int base = r * 10 + Q;                 // words 40r + 4Q
            uint4 ta4 = su4[base],      tb4 = su4[base + 1];
            uint4 ma4 = su4[base + 10], mb4 = su4[base + 11];
            uint4 ba4 = su4[base + 20], bb4 = su4[base + 21];
            __half2 t_[8] = {u2h(ta4.x),u2h(ta4.y),u2h(ta4.z),u2h(ta4.w),
                             u2h(tb4.x),u2h(tb4.y),u2h(tb4.z),u2h(tb4.w)};
            __half2 m_[8] = {u2h(ma4.x),u2h(ma4.y),u2h(ma4.z),u2h(ma4.w),
                             u2h(mb4.x),u2h(mb4.y),u2h(mb4.z),u2h(mb4.w)};
            __half2 b_[8] = {u2h(ba4.x),u2h(ba4.y),u2h(ba4.z),u2h(ba4.w),
                             u2h(bb4.x),u2h(bb4.y),u2h(bb4.z),u2h(bb4.w)};
            __half2 l_[7];
            #pragma unroll
            for (int k = 1; k <= 6; ++k) {
                __half2 s = __hadd2(t_[k], b_[k]);
                l_[k] = __hfma2(two, m_[k], s);
            }
            int gfr = f0 + r - 2;
            bool frOK = FAST || ((unsigned)gfr < (unsigned)F_DIM);
            #pragma unroll
            for (int jj = 0; jj < 4; ++jj) {
                __half2 tr = __hadd2(t_[jj+1], t_[jj+3]); tr = __hfma2(two, t_[jj+2], tr);
                __half2 br = __hadd2(b_[jj+1], b_[jj+3]); br = __hfma2(two, b_[jj+2], br);
                __half2 dx = __hmul2(__hsub2(l_[jj+3], l_[jj+1]), eighth);
                __half2 dy = __hmul2(__hsub2(br, tr), eighth);
                float2 fx = __half22float2(dx);
                float2 fy = __half22float2(dy);
                float cv = __builtin_amdgcn_sqrtf(
                    fmaf(fx.x, fx.x, fmaf(fx.y, fx.y,
                    fmaf(fy.x, fy.x, fy.y * fy.y))) + EPSF);
                int cc = 4 * Q + jj;
                if (!FAST) {
                    int gtc = t0 + cc - 2;
                    if (!(frOK & ((unsigned)gtc < (unsigned)T_DIM))) cv = 0.f;
                }
                ((__half*)s_P2)[2 * (r * FS + cc) + 1] = __float2half_rn(cv);
            }
        }
        vpass4(s_P0, (__half2*)s_tmp);   // j0 vertical: (trace,diff)
        vpass4(s_P1, s_P3);              // j1 vertical: (sxy,tin)
        __syncthreads();
    };

    for (int c = 0; c < C_DIM; ++c) {
        if (c) __syncthreads();

        const float* xp = x_in + (size_t)(b * C_DIM + c) * F_DIM * T_DIM;
        if (interior) phaseABC(xp, BoolC<true>{});
        else          phaseABC(xp, BoolC<false>{});

        __half2* tmp_h2 = (__half2*)s_tmp;

        // ====== Slot D23: j0h+j1h col-pair + entropy ; vpass4(P2->P0) ; v(u->P1) ======
        {
            const uint2* t2 = (const uint2*)tmp_h2;
            uint2 ta = t2[ryh * FH2 + mch], tb = t2[ryh * FH2 + mch + 1],
                  tc = t2[ryh * FH2 + mch + 2];
            float2 e0 = __half22float2(u2h(ta.x)), e1 = __half22float2(u2h(ta.y));
            float2 e2 = __half22float2(u2h(tb.x)), e3 = __half22float2(u2h(tb.y));
            float2 e4 = __half22float2(u2h(tc.x)), e5 = __half22float2(u2h(tc.y));
            float trc[2], dfc[2];
            trc[0] = w[0]*e0.x + w[1]*e1.x + w[2]*e2.x + w[3]*e3.x + w[4]*e4.x;
            dfc[0] = w[0]*e0.y + w[1]*e1.y + w[2]*e2.y + w[3]*e3.y + w[4]*e4.y;
            trc[1] = w[0]*e1.x + w[1]*e2.x + w[2]*e3.x + w[3]*e4.x + w[4]*e5.x;
            dfc[1] = w[0]*e1.y + w[1]*e2.y + w[2]*e3.y + w[3]*e4.y + w[4]*e5.y;

            const uint2* p3q = (const uint2*)s_P3;
            uint2 pa = p3q[ryh * FH2 + mch], pb = p3q[ryh * FH2 + mch + 1],
                  pc = p3q[ryh * FH2 + mch + 2];
            __half2 aA = h2z, aB = h2z;
            aA = __hfma2(wh2[0], u2h(pa.x), aA);
            aA = __hfma2(wh2[1], u2h(pa.y), aA);
            aA = __hfma2(wh2[2], u2h(pb.x), aA);
            aA = __hfma2(wh2[3], u2h(pb.y), aA);
            aA = __hfma2(wh2[4], u2h(pc.x), aA);
            aB = __hfma2(wh2[0], u2h(pa.y), aB);
            aB = __hfma2(wh2[1], u2h(pb.x), aB);
            aB = __hfma2(wh2[2], u2h(pb.y), aB);
            aB = __hfma2(wh2[3], u2h(pc.x), aB);
            aB = __hfma2(wh2[4], u2h(pc.y), aB);
            float2 vc[2] = {__half22float2(aA), __half22float2(aB)};
            #pragma unroll
            for (int col = 0; col < 2; ++col) {
                float trace = trc[col], diff = dfc[col];
                float2 v = vc[col];
                float disc  = __builtin_amdgcn_sqrtf(
                                  fmaxf(diff * diff + 4.f * v.x * v.x, 0.f) + EPSF);
                float l1 = fmaxf(0.5f * (trace + disc), EPSF);
                float l2 = fmaxf(0.5f * (trace - disc), EPSF);
                float inv = __builtin_amdgcn_rcpf(l1 + l2 + EPSF);
                float p1 = l1 * inv, p2 = l2 * inv;
                // v_log_f32 IS log2 — matches reference's ln(p)/ln(2)
                float ent = -(p1 * __builtin_amdgcn_logf(p1 + EPSF)
                            + p2 * __builtin_amdgcn_logf(p2 + EPSF));
                acc[0][col] += 0.5f * clamp01(ent);
                acc[4][col] += 0.5f * clamp01(v.y);
            }

            vpass4(s_P2, s_P0);          // j2 vertical: (sf,cv) -> P0
            {
                // j3 vertical: u -> P1, row-pair uint2 (odd word offset)
                const uint2* su2 = (const uint2*)s_u;
                uint2* dP1 = (uint2*)s_P1;
                for (int idx = tid; idx < 16 * FH2; idx += NTHR) {
                    int rg = idx / FH2, p = idx - rg * FH2;
                    const uint2* sp = su2 + (2 * rg + 1) * (US/2) + 1 + p;
                    uint2 vv[6];
                    #pragma unroll
                    for (int i = 0; i < 6; ++i) vv[i] = sp[i * (US/2)];
                    __half2 a0 = h2z, a1 = h2z, b0 = h2z, b1 = h2z;
                    #pragma unroll
                    for (int i = 0; i < 5; ++i) {
                        a0 = __hfma2(wh2[i], u2h(vv[i].x),     a0);
                        a1 = __hfma2(wh2[i], u2h(vv[i].y),     a1);
                        b0 = __hfma2(wh2[i], u2h(vv[i + 1].x), b0);
                        b1 = __hfma2(wh2[i], u2h(vv[i + 1].y), b1);
                    }
                    uint2 oa; oa.x = *(const unsigned*)&a0; oa.y = *(const unsigned*)&a1;
                    uint2 ob; ob.x = *(const unsigned*)&b0; ob.y = *(const unsigned*)&b1;
                    dP1[2 * rg * FH2 + p] = oa;
                    dP1[(2 * rg + 1) * FH2 + p] = ob;
                }
            }
        }
        __syncthreads();

        // ====== Slot D45: j2h (P0) + j3h (P1) col-pair ; v(x^2 -> tmp) ======
        {
            const uint2* p0q = (const uint2*)s_P0;
            uint2 qa = p0q[ryh * FH2 + mch], qb = p0q[ryh * FH2 + mch + 1],
                  qc = p0q[ryh * FH2 + mch + 2];
            __half2 sA = h2z, sB = h2z;
            sA = __hfma2(wh2[0], u2h(qa.x), sA);
            sA = __hfma2(wh2[1], u2h(qa.y), sA);
            sA = __hfma2(wh2[2], u2h(qb.x), sA);
            sA = __hfma2(wh2[3], u2h(qb.y), sA);
            sA = __hfma2(wh2[4], u2h(qc.x), sA);
            sB = __hfma2(wh2[0], u2h(qa.y), sB);
            sB = __hfma2(wh2[1], u2h(qb.x), sB);
            sB = __hfma2(wh2[2], u2h(qb.y), sB);
            sB = __hfma2(wh2[3], u2h(qc.x), sB);
            sB = __hfma2(wh2[4], u2h(qc.y), sB);
            float2 s0 = __half22float2(sA), s1 = __half22float2(sB);   // (sp, cvs)
            acc[5][0] += 0.5f * clamp01(s0.x);  acc[2][0] += 0.5f * s0.y;
            acc[5][1] += 0.5f * clamp01(s1.x);  acc[2][1] += 0.5f * s1.y;

            const uint2* p1q = (const uint2*)s_P1;
            uint2 ra = p1q[ryh * FH2 + mch], rb = p1q[ryh * FH2 + mch + 1],
                  rc = p1q[ryh * FH2 + mch + 2];
            __half2 uA = h2z, uB = h2z;
            uA = __hfma2(wh2[0], u2h(ra.x), uA);
            uA = __hfma2(wh2[1], u2h(ra.y), uA);
            uA = __hfma2(wh2[2], u2h(rb.x), uA);
            uA = __hfma2(wh2[3], u2h(rb.y), uA);
            uA = __hfma2(wh2[4], u2h(rc.x), uA);
            uB = __hfma2(wh2[0], u2h(ra.y), uB);
            uB = __hfma2(wh2[1], u2h(rb.x), uB);
            uB = __hfma2(wh2[2], u2h(rb.y), uB);
            uB = __hfma2(wh2[3], u2h(rc.x), uB);
            uB = __hfma2(wh2[4], u2h(rc.y), uB);
            float2 u0 = __half22float2(uA), u1 = __half22float2(uB);   // (ua, va)
            acc[1][0] += 0.5f * clamp01(
                __builtin_amdgcn_sqrtf(u0.x * u0.x + u0.y * u0.y + EPSF));
            acc[1][1] += 0.5f * clamp01(
                __builtin_amdgcn_sqrtf(u1.x * u1.x + u1.y * u1.y + EPSF));

            // j4 vertical: x^2 -> tmp, row-pair float2
            const float2* sx2 = (const float2*)s_x;
            float2* dt2 = (float2*)s_tmp;
            for (int idx = tid; idx < 16 * FH2; idx += NTHR) {
                int rg = idx / FH2, p = idx - rg * FH2;
                const float2* sp = sx2 + (2 * rg + 2) * (XS/2) + 1 + p;
                float2 sq[6];
                #pragma unroll
                for (int i = 0; i < 6; ++i) {
                    float2 v = sp[i * (XS/2)];
                    sq[i] = make_float2(v.x * v.x, v.y * v.y);
                }
                float aA = 0.f, bA = 0.f, aB = 0.f, bB = 0.f;
                #pragma unroll
                for (int i = 0; i < 5; ++i) {
                    aA = fmaf(w[i], sq[i].x,     aA);
                    bA = fmaf(w[i], sq[i].y,     bA);
                    aB = fmaf(w[i], sq[i + 1].x, aB);
                    bB = fmaf(w[i], sq[i + 1].y, bB);
                }
                dt2[2 * rg * FH2 + p] = make_float2(aA, bA);
                dt2[(2 * rg + 1) * FH2 + p] = make_float2(aB, bB);
            }
        }
        __syncthreads();

        // ====== Slot D6: j4h (le) col-pair + harmonic epilogue ======
        {
            const float2* tf = (const float2*)s_tmp;   // element p = x^2v cols 2p,2p+1
            float2 q0 = tf[ryh * FH2 + mch], q1 = tf[ryh * FH2 + mch + 1],
                   q2 = tf[ryh * FH2 + mch + 2];
            float le0 = w[0]*q0.x + w[1]*q0.y + w[2]*q1.x + w[3]*q1.y + w[4]*q2.x;
            float le1 = w[0]*q0.y + w[1]*q1.x + w[2]*q1.y + w[3]*q2.x + w[4]*q2.y;
            const float2* sxf = (const float2*)s_x;
            float2 xm  = sxf[(ryh + 1) * (XS/2) + mch + 2];
            float2 x0v = sxf[(ryh + 4) * (XS/2) + mch + 2];
            float2 xpv = sxf[(ryh + 7) * (XS/2) + mch + 2];
            float hA = fabsf(2.f * x0v.x - xm.x - xpv.x);
            float hB = fabsf(2.f * x0v.y - xm.y - xpv.y);
            acc[3][0] += 0.5f * clamp01(hA * __builtin_amdgcn_rcpf(le0 + EPSF));
            acc[3][1] += 0.5f * clamp01(hB * __builtin_amdgcn_rcpf(le1 + EPSF));
        }
    }

    // ---- write 6 output planes: one float2 per plane per thread, coalesced ----
    const size_t plane = (size_t)B_DIM * F_DIM * T_DIM;
    const size_t base  = (size_t)b * F_DIM * T_DIM
                       + (size_t)(f0 + ryh) * T_DIM + t0 + 2 * mch;
    #pragma unroll
    for (int k = 0; k < 6; ++k)
        *(float2*)(out + k * plane + base) = make_float2(acc[k][0], acc[k][1]);
}

extern "C" void kernel_launch(void* const* d_in, const int* in_sizes, int n_in,
                              void* d_out, int out_size, void* d_ws, size_t ws_size,
                              hipStream_t stream) {
    const float* x  = (const float*)d_in[0];
    const float* gk = (const float*)d_in[1];
    float* out = (float*)d_out;
    dim3 grid(T_DIM / TILE, F_DIM / TILE, B_DIM);   // 64 x 8 x 8 = 4096 blocks
    dim3 block(32, 16);                             // 512 threads = 8 waves
    audio_struct_fused<<<grid, block, 0, stream>>>(x, gk, out);
}